// Round 6
// baseline (428.656 us; speedup 1.0000x reference)
//
#include <hip/hip_runtime.h>

// Elman RNN via MFMA, register-chained recurrence, j-split across 4 waves.
//   H^T_{t+1} = tanh(W_hh * H^T_t + W_ih * x_t^T + b),  out = sigmoid(fc_w.h_T + fc_b)
//
// mfma 16x16 layouts (HW-verified for K=16, absmax 3.9e-3):
//   A[m][k]: m = lane&15, k = quad*4 + i
//   B[k][n]: k = quad*4 + i, n = lane&15
//   D[m][n]: n = lane&15, m = quad*4 + reg
// => a wave's packed D tile (m-tile w) IS the B-frag of k-tile kt=w for the
//    next step, in the same lane. Waves exchange B-frags through LDS with a
//    raw `s_waitcnt lgkmcnt(0); s_barrier` (vmcnt stays in flight).
//
// Measured: 4-wave/K16/2x3 chains = 166us (best); single-wave = 361us (no
// latency hiding); 3-chain+frcp_rn = 174us; pre-barrier gap work = 270us
// (work between ds_write and s_barrier delays every wave's arrival AND
// loses the post-barrier read shadow — never again).
//
// R6: K=32 MFMA compaction. mfma_f32_16x16x32_f16 stacks two 16-deep
// halves in the upper operand regs (CDNA doubling convention, cf. m74's
// 32x32x16 C/D), so B = {Bh[kt], Bh[kt+1]} and A = {Ahh[i], Ahh[i+1]}
// concatenated — the same-lane D->B identity survives. Step becomes
// 3 MFMAs, depth 2 (was 6, depth 3): c0 = ih32(bias) -> hh01; c1 = hh23.
// Next-step x-pack + ring refill live in the POST-barrier ds_read shadow;
// loop-head MFMAs issue with all operands ready.

#define RN 2048
#define RT 512
#define RI 32
#define RH 64

typedef _Float16 h4 __attribute__((ext_vector_type(4)));
typedef _Float16 h8 __attribute__((ext_vector_type(8)));
typedef float    f4 __attribute__((ext_vector_type(4)));

__device__ __forceinline__ int pk2(float a, float b) {
    return __builtin_bit_cast(int, __builtin_amdgcn_cvt_pkrtz(a, b));
}
__device__ __forceinline__ h4 pack4(float a, float b, float c, float d) {
    union { h4 v; int i[2]; } u;
    u.i[0] = pk2(a, b);
    u.i[1] = pk2(c, d);
    return u.v;
}
__device__ __forceinline__ h4 packf4(f4 v) { return pack4(v[0], v[1], v[2], v[3]); }
__device__ __forceinline__ h8 cat(h4 lo, h4 hi) {
    return __builtin_shufflevector(lo, hi, 0, 1, 2, 3, 4, 5, 6, 7);
}

__device__ __forceinline__ float tanh_fast(float z) {
    // R3-proven: 1 - 2/(e^{2z}+1); exact saturation for large |z|
    float e = __expf(2.0f * z);
    return 1.0f - __fdividef(2.0f, e + 1.0f);
}

__global__ __launch_bounds__(256, 1) void rnn_mfma4(
    const float* __restrict__ x,
    const float* __restrict__ W_ih,
    const float* __restrict__ W_hh,
    const float* __restrict__ b_ih,
    const float* __restrict__ b_hh,
    const float* __restrict__ fc_w,
    const float* __restrict__ fc_b,
    float* __restrict__ out)
{
    const int tid  = threadIdx.x;
    const int w    = tid >> 6;      // wave id = m-tile
    const int lane = tid & 63;
    const int col  = lane & 15;     // sample within group
    const int quad = lane >> 4;     // 0..3
    const int g    = blockIdx.x;

    // h exchange: [buf][kt*64 + lane] -> 8B B-frag. 2-way bank alias only.
    __shared__ unsigned long long hb[2][4 * 64];
    __shared__ float ob[4][16];

    // ---- A-frags for my m-tile, kt ROTATED: slot i holds kt=(w+i)&3 ----
    // slot 0 = own tile (register-local B), slots 1..3 = foreign (LDS B).
    h4 Ahh[4];
#pragma unroll
    for (int i = 0; i < 4; ++i) {
        const int kt = (w + i) & 3;
        f4 v = *(const f4*)(W_hh + (w * 16 + col) * RH + kt * 16 + quad * 4);
        Ahh[i] = packf4(v);
    }
    h4 Aih[2];
#pragma unroll
    for (int kt = 0; kt < 2; ++kt) {
        f4 v = *(const f4*)(W_ih + (w * 16 + col) * RI + kt * 16 + quad * 4);
        Aih[kt] = packf4(v);
    }
    // K=32 operand pairs (built once; lo half = first tile, hi = second)
    const h8 a_ih  = cat(Aih[0], Aih[1]);   // k = 0..31 of W_ih row
    const h8 a_h01 = cat(Ahh[0], Ahh[1]);   // k-tiles (w+0)&3, (w+1)&3
    const h8 a_h23 = cat(Ahh[2], Ahh[3]);   // k-tiles (w+2)&3, (w+3)&3
    f4 biasv;
    {
        f4 bi = *(const f4*)(b_ih + w * 16 + quad * 4);
        f4 bh = *(const f4*)(b_hh + w * 16 + quad * 4);
        biasv = bi + bh;
    }

    // ---- x stream: 4-step static ring; bx packed ONE STEP AHEAD so the
    //      loop-head MFMA has ready operands ----
    const float* xb = x + (size_t)(g * 16 + col) * (RT * RI);
    f4 xbuf[4][2];
#pragma unroll
    for (int s = 0; s < 4; ++s) {
        xbuf[s][0] = *(const f4*)(xb + s * RI + quad * 4);
        xbuf[s][1] = *(const f4*)(xb + s * RI + 16 + quad * 4);
    }
    h4 bxc0 = packf4(xbuf[0][0]);
    h4 bxc1 = packf4(xbuf[0][1]);

    // h0 = ones, already in B-frag layout. Bh[i] corresponds to kt=(w+i)&3;
    // Bh[0] is my OWN tile (from my local pack, never from LDS).
    h4 Bh[4];
#pragma unroll
    for (int i = 0; i < 4; ++i) Bh[i] = pack4(1.f, 1.f, 1.f, 1.f);
    f4 hv; // f32 h of final step (my m-tile rows), for epilogue

    for (int t4 = 0; t4 < RT; t4 += 4) {
#pragma unroll
        for (int s = 0; s < 4; ++s) {
            const int t = t4 + s;

            // 3 MFMAs, depth 2. c0: ih (operands ready at entry) -> hh01
            // (Bh[1] is the FIRST ds_read -> lgkmcnt(2) suffices); c1: hh23.
            h8 bx  = cat(bxc0, bxc1);
            h8 b01 = cat(Bh[0], Bh[1]);
            h8 b23 = cat(Bh[2], Bh[3]);
            f4 c0 = __builtin_amdgcn_mfma_f32_16x16x32_f16(a_ih,  bx,  biasv, 0, 0, 0);
            c0    = __builtin_amdgcn_mfma_f32_16x16x32_f16(a_h01, b01, c0,    0, 0, 0);
            f4 c1 = __builtin_amdgcn_mfma_f32_16x16x32_f16(a_h23, b23, f4{0.f, 0.f, 0.f, 0.f}, 0, 0, 0);
            f4 acc = c0 + c1;

            hv[0] = tanh_fast(acc[0]);
            hv[1] = tanh_fast(acc[1]);
            hv[2] = tanh_fast(acc[2]);
            hv[3] = tanh_fast(acc[3]);

            // publish my D tile as next step's B-frag kt = w
            const int p = t & 1;
            h4 hpk = packf4(hv);
            hb[p][w * 64 + lane] = __builtin_bit_cast(unsigned long long, hpk);
            // RAW BARRIER: wait only on the LDS write (lgkmcnt), NOT on the
            // global x-prefetch (vmcnt) — loads stay in flight across steps.
            asm volatile("s_waitcnt lgkmcnt(0)\n\ts_barrier" ::: "memory");
            Bh[0] = hpk; // own tile, no LDS round-trip
            Bh[1] = __builtin_bit_cast(h4, hb[p][(((w + 1) & 3)) * 64 + lane]);
            Bh[2] = __builtin_bit_cast(h4, hb[p][(((w + 2) & 3)) * 64 + lane]);
            Bh[3] = __builtin_bit_cast(h4, hb[p][(((w + 3) & 3)) * 64 + lane]);

            // ---- post-barrier ds_read shadow: next-step x-pack + refill ----
            const int sn = (s + 1) & 3;
            h4 bn0 = packf4(xbuf[sn][0]);
            h4 bn1 = packf4(xbuf[sn][1]);
            int tn = t + 4; if (tn > RT - 1) tn = RT - 1;
            xbuf[s][0] = *(const f4*)(xb + tn * RI + quad * 4);
            xbuf[s][1] = *(const f4*)(xb + tn * RI + 16 + quad * 4);
            bxc0 = bn0;
            bxc1 = bn1;
        }
    }

    // ---- epilogue: out[n] = sigmoid(sum_j fc_w[j] h[n][j] + fc_b) ----
    {
        f4 wv = *(const f4*)(fc_w + w * 16 + quad * 4);
        float s = wv[0] * hv[0] + wv[1] * hv[1] + wv[2] * hv[2] + wv[3] * hv[3];
        s += __shfl_xor(s, 16, 64);
        s += __shfl_xor(s, 32, 64); // all lanes: partial over my 16 hidden units
        if (quad == 0) ob[w][col] = s;
        __syncthreads();
        if (w == 0 && lane < 16) {
            float logit = ob[0][lane] + ob[1][lane] + ob[2][lane] + ob[3][lane] + fc_b[0];
            out[g * 16 + lane] = __fdividef(1.0f, 1.0f + __expf(-logit));
        }
    }
}

extern "C" void kernel_launch(void* const* d_in, const int* in_sizes, int n_in,
                              void* d_out, int out_size, void* d_ws, size_t ws_size,
                              hipStream_t stream) {
    rnn_mfma4<<<RN / 16, 256, 0, stream>>>(
        (const float*)d_in[0], (const float*)d_in[1], (const float*)d_in[2],
        (const float*)d_in[3], (const float*)d_in[4], (const float*)d_in[5],
        (const float*)d_in[6], (float*)d_out);
}

// Round 7
// 293.867 us; speedup vs baseline: 1.4587x; 1.4587x over previous
//
#include <hip/hip_runtime.h>

// Elman RNN via MFMA, register-chained recurrence, j-split across 4 waves.
//   H^T_{t+1} = tanh(W_hh * H^T_t + W_ih * x_t^T + b),  out = sigmoid(fc_w.h_T + fc_b)
//
// mfma_f32_16x16x16f16 layouts (HW-verified, absmax 3.9e-3):
//   A[m][k]: m = lane&15, k = quad*4 + i
//   B[k][n]: k = quad*4 + i, n = lane&15
//   D[m][n]: n = lane&15, m = quad*4 + reg
// => a wave's packed D tile (m-tile w) IS the B-frag of k-tile kt=w for the
//    next step, in the same lane. Waves exchange B-frags through LDS with a
//    raw `s_waitcnt lgkmcnt(0); s_barrier` (vmcnt stays in flight).
//
// Measured scoreboard: R3 skeleton (this file's structure) = 166us BEST.
// single-wave register-closed = 361us; 3-chain+frcp_rn = 174us; pre-barrier
// gap work = 270us (delays all waves' barrier arrival); K=32 MFMA = 284us
// (longer dep latency + cat() v_movs on the read->MFMA path). Structure is
// latency-pinned; only remaining soft spot = tanh dependency chain.
//
// R7 (this version): tanh chain 6 -> 3 dependent levels, zero structural
// change vs R3:
//  (a) weights & bias pre-scaled by 2*log2(e) at fragment-load time, so the
//      MFMA accumulator IS the exp2 argument (kills 2 muls). h stays
//      unscaled (tanh output) => recurrence/epilogue untouched; fp16
//      relative precision is scale-invariant.
//  (b) tanh = fmaf(-2, v_rcp(exp2(acc)+1), 1): v_exp_f32 -> v_add -> v_rcp
//      -> v_fma, all single-instruction. Exact saturation at +-1 for large
//      |acc| (exp2->inf/0).

#define RN 2048
#define RT 512
#define RI 32
#define RH 64

typedef _Float16 h4 __attribute__((ext_vector_type(4)));
typedef float    f4 __attribute__((ext_vector_type(4)));

__device__ __forceinline__ int pk2(float a, float b) {
    return __builtin_bit_cast(int, __builtin_amdgcn_cvt_pkrtz(a, b));
}
__device__ __forceinline__ h4 pack4(float a, float b, float c, float d) {
    union { h4 v; int i[2]; } u;
    u.i[0] = pk2(a, b);
    u.i[1] = pk2(c, d);
    return u.v;
}
__device__ __forceinline__ h4 packf4(f4 v) { return pack4(v[0], v[1], v[2], v[3]); }

// acc is pre-scaled: acc = 2*log2(e) * z.  tanh(z) = 1 - 2/(2^acc + 1).
__device__ __forceinline__ float tanh_pre(float acc) {
    float e = __builtin_amdgcn_exp2f(acc);        // v_exp_f32
    float r = __builtin_amdgcn_rcpf(e + 1.0f);    // v_rcp_f32
    return fmaf(-2.0f, r, 1.0f);                  // v_fma_f32
}

#define TSCALE 2.8853900817779268f   // 2*log2(e)

__global__ __launch_bounds__(256, 1) void rnn_mfma4(
    const float* __restrict__ x,
    const float* __restrict__ W_ih,
    const float* __restrict__ W_hh,
    const float* __restrict__ b_ih,
    const float* __restrict__ b_hh,
    const float* __restrict__ fc_w,
    const float* __restrict__ fc_b,
    float* __restrict__ out)
{
    const int tid  = threadIdx.x;
    const int w    = tid >> 6;      // wave id = m-tile
    const int lane = tid & 63;
    const int col  = lane & 15;     // sample within group
    const int quad = lane >> 4;     // 0..3
    const int g    = blockIdx.x;

    // h exchange: [buf][kt*64 + lane] -> 8B B-frag. 2-way bank alias only.
    __shared__ unsigned long long hb[2][4 * 64];
    __shared__ float ob[4][16];

    // ---- A-frags for my m-tile, kt ROTATED: slot i holds kt=(w+i)&3 ----
    // slot 0 = own tile (register-local B), slots 1..3 = foreign (LDS B).
    // All weight frags and the bias are PRE-SCALED by 2*log2(e).
    h4 Ahh[4];
#pragma unroll
    for (int i = 0; i < 4; ++i) {
        const int kt = (w + i) & 3;
        f4 v = *(const f4*)(W_hh + (w * 16 + col) * RH + kt * 16 + quad * 4);
        Ahh[i] = packf4(v * TSCALE);
    }
    h4 Aih[2];
#pragma unroll
    for (int kt = 0; kt < 2; ++kt) {
        f4 v = *(const f4*)(W_ih + (w * 16 + col) * RI + kt * 16 + quad * 4);
        Aih[kt] = packf4(v * TSCALE);
    }
    f4 biasv;
    {
        f4 bi = *(const f4*)(b_ih + w * 16 + quad * 4);
        f4 bh = *(const f4*)(b_hh + w * 16 + quad * 4);
        biasv = (bi + bh) * TSCALE;
    }

    // ---- x stream for this lane's sample, 4-step static ring ----
    const float* xb = x + (size_t)(g * 16 + col) * (RT * RI);
    f4 xbuf[4][2];
#pragma unroll
    for (int s = 0; s < 4; ++s) {
        xbuf[s][0] = *(const f4*)(xb + s * RI + quad * 4);
        xbuf[s][1] = *(const f4*)(xb + s * RI + 16 + quad * 4);
    }

    // h0 = ones, already in B-frag layout. Bh[i] corresponds to kt=(w+i)&3;
    // Bh[0] is my OWN tile (from my local pack, never from LDS).
    h4 Bh[4];
#pragma unroll
    for (int i = 0; i < 4; ++i) Bh[i] = pack4(1.f, 1.f, 1.f, 1.f);
    f4 hv; // f32 h of final step (my m-tile rows), for epilogue

    for (int t4 = 0; t4 < RT; t4 += 4) {
#pragma unroll
        for (int s = 0; s < 4; ++s) {
            const int t = t4 + s;
            h4 bx0 = packf4(xbuf[s][0]);
            h4 bx1 = packf4(xbuf[s][1]);
            int tn = t + 4; if (tn > RT - 1) tn = RT - 1;
            xbuf[s][0] = *(const f4*)(xb + tn * RI + quad * 4);
            xbuf[s][1] = *(const f4*)(xb + tn * RI + 16 + quad * 4);

            // two balanced 3-deep MFMA chains (R3 arrangement, best measured);
            // x-part is independent of Bh, so it issues while the ds_reads
            // of h are still in flight.
            f4 c0 = __builtin_amdgcn_mfma_f32_16x16x16f16(Aih[0], bx0, biasv, 0, 0, 0);
            f4 c1 = __builtin_amdgcn_mfma_f32_16x16x16f16(Aih[1], bx1, f4{0.f, 0.f, 0.f, 0.f}, 0, 0, 0);
            c0 = __builtin_amdgcn_mfma_f32_16x16x16f16(Ahh[0], Bh[0], c0, 0, 0, 0); // own, local
            c1 = __builtin_amdgcn_mfma_f32_16x16x16f16(Ahh[1], Bh[1], c1, 0, 0, 0); // foreign 1
            c0 = __builtin_amdgcn_mfma_f32_16x16x16f16(Ahh[2], Bh[2], c0, 0, 0, 0); // foreign 2
            c1 = __builtin_amdgcn_mfma_f32_16x16x16f16(Ahh[3], Bh[3], c1, 0, 0, 0); // foreign 3
            f4 acc = c0 + c1;   // acc = 2*log2(e) * z

            hv[0] = tanh_pre(acc[0]);
            hv[1] = tanh_pre(acc[1]);
            hv[2] = tanh_pre(acc[2]);
            hv[3] = tanh_pre(acc[3]);

            // publish my D tile as next step's B-frag kt = w
            const int p = t & 1;
            h4 hpk = packf4(hv);
            hb[p][w * 64 + lane] = __builtin_bit_cast(unsigned long long, hpk);
            // RAW BARRIER: wait only on the LDS write (lgkmcnt), NOT on the
            // global x-prefetch (vmcnt) — loads stay in flight across steps.
            asm volatile("s_waitcnt lgkmcnt(0)\n\ts_barrier" ::: "memory");
            Bh[0] = hpk; // own tile, no LDS round-trip
            Bh[1] = __builtin_bit_cast(h4, hb[p][(((w + 1) & 3)) * 64 + lane]);
            Bh[2] = __builtin_bit_cast(h4, hb[p][(((w + 2) & 3)) * 64 + lane]);
            Bh[3] = __builtin_bit_cast(h4, hb[p][(((w + 3) & 3)) * 64 + lane]);
        }
    }

    // ---- epilogue: out[n] = sigmoid(sum_j fc_w[j] h[n][j] + fc_b) ----
    {
        f4 wv = *(const f4*)(fc_w + w * 16 + quad * 4);
        float s = wv[0] * hv[0] + wv[1] * hv[1] + wv[2] * hv[2] + wv[3] * hv[3];
        s += __shfl_xor(s, 16, 64);
        s += __shfl_xor(s, 32, 64); // all lanes: partial over my 16 hidden units
        if (quad == 0) ob[w][col] = s;
        __syncthreads();
        if (w == 0 && lane < 16) {
            float logit = ob[0][lane] + ob[1][lane] + ob[2][lane] + ob[3][lane] + fc_b[0];
            out[g * 16 + lane] = __fdividef(1.0f, 1.0f + __expf(-logit));
        }
    }
}

extern "C" void kernel_launch(void* const* d_in, const int* in_sizes, int n_in,
                              void* d_out, int out_size, void* d_ws, size_t ws_size,
                              hipStream_t stream) {
    rnn_mfma4<<<RN / 16, 256, 0, stream>>>(
        (const float*)d_in[0], (const float*)d_in[1], (const float*)d_in[2],
        (const float*)d_in[3], (const float*)d_in[4], (const float*)d_in[5],
        (const float*)d_in[6], (float*)d_out);
}

// Round 8
// 282.979 us; speedup vs baseline: 1.5148x; 1.0385x over previous
//
#include <hip/hip_runtime.h>

// Elman RNN via MFMA, register-chained recurrence, j-split across 4 waves.
//   H^T_{t+1} = tanh(W_hh * H^T_t + W_ih * x_t^T + b),  out = sigmoid(fc_w.h_T + fc_b)
//
// mfma_f32_16x16x16f16 layouts (HW-verified, absmax 3.9e-3):
//   A[m][k]: m = lane&15, k = quad*4 + i
//   B[k][n]: k = quad*4 + i, n = lane&15
//   D[m][n]: n = lane&15, m = quad*4 + reg
// => a wave's packed D tile (m-tile w) IS the B-frag of k-tile kt=w for the
//    next step, in the same lane. Waves exchange B-frags through LDS with a
//    raw `s_waitcnt lgkmcnt(0); s_barrier` (vmcnt stays in flight).
//
// Scoreboard (per-dispatch): R3 2x3-chain = 166us; R7 = R3 + pre-scaled
// weights (acc = 2log2e*z) + 3-level tanh = 149.7us BEST. Failures: 1-wave
// register-closed 361 (no hiding); frcp_rn 174; pre-barrier gap work 270;
// K=32 mfma 284. Counters at R7: VALU-issue ~91cy, MFMA ~46cy, stall ~565cy
// of a 702cy step. Single-wave datapoint back-solves MFMA dep latency
// ~100cy => the 2 SEQUENTIAL foreign MFMAs after the ds_read (~200cy) are
// the largest cuttable segment.
//
// R8: depth-1 foreign dataflow. All 3 foreign MFMAs are independent roots
// (C=0) issued right at read-complete; local work is a depth-2 chain
// (ih0+bias -> own) plus an ih1 root; small f4 add tree merges the 5
// accumulators. Post-read MFMA segment ~200 -> ~110cy. (R4's "3-chain" test
// was polluted by frcp_rn and still stacked foreigns on prior MFMAs — this
// is the clean parallel-roots test.) Everything else byte-identical to R7.

#define RN 2048
#define RT 512
#define RI 32
#define RH 64

typedef _Float16 h4 __attribute__((ext_vector_type(4)));
typedef float    f4 __attribute__((ext_vector_type(4)));

__device__ __forceinline__ int pk2(float a, float b) {
    return __builtin_bit_cast(int, __builtin_amdgcn_cvt_pkrtz(a, b));
}
__device__ __forceinline__ h4 pack4(float a, float b, float c, float d) {
    union { h4 v; int i[2]; } u;
    u.i[0] = pk2(a, b);
    u.i[1] = pk2(c, d);
    return u.v;
}
__device__ __forceinline__ h4 packf4(f4 v) { return pack4(v[0], v[1], v[2], v[3]); }

// acc is pre-scaled: acc = 2*log2(e) * z.  tanh(z) = 1 - 2/(2^acc + 1).
__device__ __forceinline__ float tanh_pre(float acc) {
    float e = __builtin_amdgcn_exp2f(acc);        // v_exp_f32
    float r = __builtin_amdgcn_rcpf(e + 1.0f);    // v_rcp_f32
    return fmaf(-2.0f, r, 1.0f);                  // v_fma_f32
}

#define TSCALE 2.8853900817779268f   // 2*log2(e)

__global__ __launch_bounds__(256, 1) void rnn_mfma4(
    const float* __restrict__ x,
    const float* __restrict__ W_ih,
    const float* __restrict__ W_hh,
    const float* __restrict__ b_ih,
    const float* __restrict__ b_hh,
    const float* __restrict__ fc_w,
    const float* __restrict__ fc_b,
    float* __restrict__ out)
{
    const int tid  = threadIdx.x;
    const int w    = tid >> 6;      // wave id = m-tile
    const int lane = tid & 63;
    const int col  = lane & 15;     // sample within group
    const int quad = lane >> 4;     // 0..3
    const int g    = blockIdx.x;

    // h exchange: [buf][kt*64 + lane] -> 8B B-frag. 2-way bank alias only.
    __shared__ unsigned long long hb[2][4 * 64];
    __shared__ float ob[4][16];

    // ---- A-frags for my m-tile, kt ROTATED: slot i holds kt=(w+i)&3 ----
    // slot 0 = own tile (register-local B), slots 1..3 = foreign (LDS B).
    // All weight frags and the bias are PRE-SCALED by 2*log2(e).
    h4 Ahh[4];
#pragma unroll
    for (int i = 0; i < 4; ++i) {
        const int kt = (w + i) & 3;
        f4 v = *(const f4*)(W_hh + (w * 16 + col) * RH + kt * 16 + quad * 4);
        Ahh[i] = packf4(v * TSCALE);
    }
    h4 Aih[2];
#pragma unroll
    for (int kt = 0; kt < 2; ++kt) {
        f4 v = *(const f4*)(W_ih + (w * 16 + col) * RI + kt * 16 + quad * 4);
        Aih[kt] = packf4(v * TSCALE);
    }
    f4 biasv;
    {
        f4 bi = *(const f4*)(b_ih + w * 16 + quad * 4);
        f4 bh = *(const f4*)(b_hh + w * 16 + quad * 4);
        biasv = (bi + bh) * TSCALE;
    }

    // ---- x stream for this lane's sample, 4-step static ring ----
    const float* xb = x + (size_t)(g * 16 + col) * (RT * RI);
    f4 xbuf[4][2];
#pragma unroll
    for (int s = 0; s < 4; ++s) {
        xbuf[s][0] = *(const f4*)(xb + s * RI + quad * 4);
        xbuf[s][1] = *(const f4*)(xb + s * RI + 16 + quad * 4);
    }

    // h0 = ones, already in B-frag layout. Bh[i] corresponds to kt=(w+i)&3;
    // Bh[0] is my OWN tile (from my local pack, never from LDS).
    h4 Bh[4];
#pragma unroll
    for (int i = 0; i < 4; ++i) Bh[i] = pack4(1.f, 1.f, 1.f, 1.f);
    f4 hv; // f32 h of final step (my m-tile rows), for epilogue

    for (int t4 = 0; t4 < RT; t4 += 4) {
#pragma unroll
        for (int s = 0; s < 4; ++s) {
            const int t = t4 + s;
            h4 bx0 = packf4(xbuf[s][0]);
            h4 bx1 = packf4(xbuf[s][1]);
            int tn = t + 4; if (tn > RT - 1) tn = RT - 1;
            xbuf[s][0] = *(const f4*)(xb + tn * RI + quad * 4);
            xbuf[s][1] = *(const f4*)(xb + tn * RI + 16 + quad * 4);

            // Depth-1 foreign dataflow: local roots first (operands ready at
            // entry, issue into the ds_read latency window), then the three
            // INDEPENDENT foreign MFMAs at read-complete, then the local
            // depth-2 own MFMA (its C arrives ~read-time). f4 add tree merges.
            const f4 z{0.f, 0.f, 0.f, 0.f};
            f4 ca = __builtin_amdgcn_mfma_f32_16x16x16f16(Aih[0], bx0, biasv, 0, 0, 0);
            f4 cb = __builtin_amdgcn_mfma_f32_16x16x16f16(Aih[1], bx1, z, 0, 0, 0);
            f4 f1 = __builtin_amdgcn_mfma_f32_16x16x16f16(Ahh[1], Bh[1], z, 0, 0, 0); // foreign 1
            f4 f2 = __builtin_amdgcn_mfma_f32_16x16x16f16(Ahh[2], Bh[2], z, 0, 0, 0); // foreign 2
            f4 f3 = __builtin_amdgcn_mfma_f32_16x16x16f16(Ahh[3], Bh[3], z, 0, 0, 0); // foreign 3
            ca = __builtin_amdgcn_mfma_f32_16x16x16f16(Ahh[0], Bh[0], ca, 0, 0, 0);   // own, local
            f4 acc = (ca + cb) + ((f1 + f2) + f3);   // acc = 2*log2(e) * z

            hv[0] = tanh_pre(acc[0]);
            hv[1] = tanh_pre(acc[1]);
            hv[2] = tanh_pre(acc[2]);
            hv[3] = tanh_pre(acc[3]);

            // publish my D tile as next step's B-frag kt = w
            const int p = t & 1;
            h4 hpk = packf4(hv);
            hb[p][w * 64 + lane] = __builtin_bit_cast(unsigned long long, hpk);
            // RAW BARRIER: wait only on the LDS write (lgkmcnt), NOT on the
            // global x-prefetch (vmcnt) — loads stay in flight across steps.
            asm volatile("s_waitcnt lgkmcnt(0)\n\ts_barrier" ::: "memory");
            Bh[0] = hpk; // own tile, no LDS round-trip
            Bh[1] = __builtin_bit_cast(h4, hb[p][(((w + 1) & 3)) * 64 + lane]);
            Bh[2] = __builtin_bit_cast(h4, hb[p][(((w + 2) & 3)) * 64 + lane]);
            Bh[3] = __builtin_bit_cast(h4, hb[p][(((w + 3) & 3)) * 64 + lane]);
        }
    }

    // ---- epilogue: out[n] = sigmoid(sum_j fc_w[j] h[n][j] + fc_b) ----
    {
        f4 wv = *(const f4*)(fc_w + w * 16 + quad * 4);
        float s = wv[0] * hv[0] + wv[1] * hv[1] + wv[2] * hv[2] + wv[3] * hv[3];
        s += __shfl_xor(s, 16, 64);
        s += __shfl_xor(s, 32, 64); // all lanes: partial over my 16 hidden units
        if (quad == 0) ob[w][col] = s;
        __syncthreads();
        if (w == 0 && lane < 16) {
            float logit = ob[0][lane] + ob[1][lane] + ob[2][lane] + ob[3][lane] + fc_b[0];
            out[g * 16 + lane] = __fdividef(1.0f, 1.0f + __expf(-logit));
        }
    }
}

extern "C" void kernel_launch(void* const* d_in, const int* in_sizes, int n_in,
                              void* d_out, int out_size, void* d_ws, size_t ws_size,
                              hipStream_t stream) {
    rnn_mfma4<<<RN / 16, 256, 0, stream>>>(
        (const float*)d_in[0], (const float*)d_in[1], (const float*)d_in[2],
        (const float*)d_in[3], (const float*)d_in[4], (const float*)d_in[5],
        (const float*)d_in[6], (float*)d_out);
}